// Round 1
// baseline (1240.743 us; speedup 1.0000x reference)
//
#include <hip/hip_runtime.h>
#include <math.h>

#define B_ 2
#define H_ 64
#define W_ 64
#define C_ 256
#define G_ 16
#define K_ 9
#define CG_ 16
#define HW_ (H_*W_)          // 4096
#define M_ (B_*HW_)          // 8192
#define C4_ (4*C_)           // 1024
#define OFFN_ (G_*K_*2)      // 288
#define MSKN_ (G_*K_)        // 144
#define UH_ 128
#define UW_ 128
#define MUP_ (B_*UH_*UW_)    // 32768
#define KUP_ (9*C_)          // 2304
#define NOUT_ 128

__device__ __forceinline__ float gelu_f(float x){
  return 0.5f * x * (1.f + erff(x * 0.70710678118654752440f));
}
__device__ __forceinline__ float sigmoid_f(float x){ return 1.f/(1.f+expf(-x)); }

// block-wide (sum,sumsq) reduce; works for blockDim.x in {128,256}
__device__ __forceinline__ void block_sum2(float& s, float& ss, float* sm){
  #pragma unroll
  for (int off=32; off>0; off>>=1){ s += __shfl_down(s, off); ss += __shfl_down(ss, off); }
  int lane = threadIdx.x & 63, wid = threadIdx.x >> 6;
  if (lane == 0){ sm[wid] = s; sm[4+wid] = ss; }
  __syncthreads();
  float a = 0.f, b = 0.f;
  int nw = blockDim.x >> 6;
  for (int i=0;i<nw;i++){ a += sm[i]; b += sm[4+i]; }
  s = a; ss = b;
}

// block-wide (sum,max) reduce; blockDim.x == 256
__device__ __forceinline__ void block_summax(float& s, float& m, float* sm){
  #pragma unroll
  for (int off=32; off>0; off>>=1){ s += __shfl_down(s, off); m = fmaxf(m, __shfl_down(m, off)); }
  int lane = threadIdx.x & 63, wid = threadIdx.x >> 6;
  if (lane == 0){ sm[wid] = s; sm[4+wid] = m; }
  __syncthreads();
  float a = 0.f, b = -3.4e38f;
  int nw = blockDim.x >> 6;
  for (int i=0;i<nw;i++){ a += sm[i]; b = fmaxf(b, sm[4+i]); }
  s = a; m = b;
}

// ---------------- CBAM ----------------
// partial channel pool: grid (16 chunks, B), 256 threads (one per channel)
__global__ __launch_bounds__(256) void k_chpool(const float* __restrict__ Xin,
      float* __restrict__ psum, float* __restrict__ pmax){
  int chunk = blockIdx.x, b = blockIdx.y; int c = threadIdx.x;
  const float* p = Xin + (((size_t)b*HW_) + chunk*256)*C_ + c;
  float s = 0.f, m = -3.4e38f;
  for (int i=0;i<256;i++){ float v = p[(size_t)i*C_]; s += v; m = fmaxf(m, v); }
  psum[(b*16+chunk)*C_+c] = s; pmax[(b*16+chunk)*C_+c] = m;
}

// channel attention fc: 1 block, 512 threads
__global__ __launch_bounds__(512) void k_ca(const float* __restrict__ psum, const float* __restrict__ pmax,
    const float* __restrict__ w1, const float* __restrict__ w2, float* __restrict__ ca){
  __shared__ float pm[2][256], px[2][256], hh[2][2][16];
  int t = threadIdx.x;
  {
    int b = t >> 8, c = t & 255;
    float s = 0.f, m = -3.4e38f;
    for (int ch=0; ch<16; ch++){ s += psum[(b*16+ch)*256+c]; m = fmaxf(m, pmax[(b*16+ch)*256+c]); }
    pm[b][c] = s * (1.f/4096.f); px[b][c] = m;
  }
  __syncthreads();
  if (t < 64){
    int b = t >> 5, typ = (t >> 4) & 1, j = t & 15;
    const float* src = typ ? px[b] : pm[b];
    float a = 0.f;
    for (int c2=0;c2<256;c2++) a += src[c2]*w1[c2*16+j];
    hh[b][typ][j] = fmaxf(a, 0.f);
  }
  __syncthreads();
  {
    int b = t >> 8, c = t & 255;
    float a = 0.f;
    for (int j=0;j<16;j++) a += (hh[b][0][j]+hh[b][1][j]) * w2[j*256+c];
    ca[b*256+c] = sigmoid_f(a);
  }
}

// apply channel attention, produce spatial mean/max planes
__global__ __launch_bounds__(256) void k_apply_ca(const float* __restrict__ Xin, float* __restrict__ X,
    const float* __restrict__ ca, float* __restrict__ smean, float* __restrict__ smax){
  __shared__ float sm[12];
  int pix = blockIdx.x, c = threadIdx.x;
  int b = pix >> 12;
  float v = Xin[(size_t)pix*C_+c] * ca[b*C_+c];
  X[(size_t)pix*C_+c] = v;
  float s = v, m = v;
  block_summax(s, m, sm);
  if (c == 0){ smean[pix] = s * (1.f/C_); smax[pix] = m; }
}

// spatial attention 7x7 conv (2ch->1) + sigmoid; 1 thread per pixel
__global__ __launch_bounds__(256) void k_sa(const float* __restrict__ smean, const float* __restrict__ smax,
    const float* __restrict__ w, float* __restrict__ sa){
  int pix = blockIdx.x*256 + threadIdx.x;
  if (pix >= M_) return;
  int b = pix >> 12, hw = pix & 4095, h = hw >> 6, ww = hw & 63;
  float s = 0.f;
  for (int ky=0;ky<7;ky++){
    int hh = h + ky - 3; if (hh < 0 || hh >= H_) continue;
    for (int kx=0;kx<7;kx++){
      int xx = ww + kx - 3; if (xx < 0 || xx >= W_) continue;
      int q = (b<<12) + (hh<<6) + xx;
      s += smean[q]*w[(ky*7+kx)*2+0] + smax[q]*w[(ky*7+kx)*2+1];
    }
  }
  sa[pix] = sigmoid_f(s);
}

// x = LN(x * sa) in-place
__global__ __launch_bounds__(256) void k_mul_ln(float* __restrict__ X, const float* __restrict__ sa,
    const float* __restrict__ g, const float* __restrict__ b){
  __shared__ float sm[12];
  int pix = blockIdx.x, c = threadIdx.x;
  float v = X[(size_t)pix*C_+c] * sa[pix];
  float s = v, ss = v*v;
  block_sum2(s, ss, sm);
  float mean = s * (1.f/C_), var = ss*(1.f/C_) - mean*mean;
  float r = rsqrtf(var + 1e-6f);
  X[(size_t)pix*C_+c] = (v-mean)*r*g[c] + b[c];
}

// generic per-pixel LayerNorm over C channels
__global__ __launch_bounds__(256) void k_ln(const float* __restrict__ In, float* __restrict__ Out,
    const float* __restrict__ g, const float* __restrict__ b){
  __shared__ float sm[12];
  int pix = blockIdx.x, c = threadIdx.x;
  float v = In[(size_t)pix*C_+c];
  float s = v, ss = v*v;
  block_sum2(s, ss, sm);
  float mean = s * (1.f/C_), var = ss*(1.f/C_) - mean*mean;
  float r = rsqrtf(var + 1e-6f);
  Out[(size_t)pix*C_+c] = (v-mean)*r*g[c] + b[c];
}

// depthwise 3x3 + bias + LN + GELU  (DCNv3 f-branch)
__global__ __launch_bounds__(256) void k_dw3(const float* __restrict__ T, float* __restrict__ F,
    const float* __restrict__ w, const float* __restrict__ bias,
    const float* __restrict__ g, const float* __restrict__ bb){
  __shared__ float sm[12];
  int pix = blockIdx.x, c = threadIdx.x;
  int b = pix >> 12, hw = pix & 4095, h = hw >> 6, ww = hw & 63;
  float acc = bias[c];
  for (int ky=0;ky<3;ky++){
    int hh = h + ky - 1; if (hh < 0 || hh >= H_) continue;
    for (int kx=0;kx<3;kx++){
      int xx = ww + kx - 1; if (xx < 0 || xx >= W_) continue;
      acc += T[(((size_t)b*H_+hh)*W_+xx)*C_ + c] * w[(ky*3+kx)*C_ + c];
    }
  }
  float s = acc, ss = acc*acc;
  block_sum2(s, ss, sm);
  float mean = s * (1.f/C_), var = ss*(1.f/C_) - mean*mean;
  float r = rsqrtf(var + 1e-6f);
  F[(size_t)pix*C_ + c] = gelu_f((acc-mean)*r*g[c] + bb[c]);
}

// depthwise 7x7 + bias + LN (LEFFN front)
__global__ __launch_bounds__(256) void k_dw7(const float* __restrict__ T, float* __restrict__ Out,
    const float* __restrict__ w, const float* __restrict__ bias,
    const float* __restrict__ g, const float* __restrict__ bb){
  __shared__ float sm[12];
  int pix = blockIdx.x, c = threadIdx.x;
  int b = pix >> 12, hw = pix & 4095, h = hw >> 6, ww = hw & 63;
  float acc = bias[c];
  for (int ky=0;ky<7;ky++){
    int hh = h + ky - 3; if (hh < 0 || hh >= H_) continue;
    for (int kx=0;kx<7;kx++){
      int xx = ww + kx - 3; if (xx < 0 || xx >= W_) continue;
      acc += T[(((size_t)b*H_+hh)*W_+xx)*C_ + c] * w[(ky*7+kx)*C_ + c];
    }
  }
  float s = acc, ss = acc*acc;
  block_sum2(s, ss, sm);
  float mean = s * (1.f/C_), var = ss*(1.f/C_) - mean*mean;
  float r = rsqrtf(var + 1e-6f);
  Out[(size_t)pix*C_ + c] = (acc-mean)*r*g[c] + bb[c];
}

// tiled SGEMM: Out[M,N] = A[M,K] @ Bw[K,N] (+epilogues). M % 64 == 0, K % 16 == 0, N % 4 == 0.
// EP: 0=bias, 1=bias+gelu, 2=res1+bias..., 3=res1+res2+gamma*(acc+bias)
template<int EP>
__global__ __launch_bounds__(256) void k_gemm(
    const float* __restrict__ A, const float* __restrict__ Bw,
    float* __restrict__ Out, const float* __restrict__ bias,
    const float* __restrict__ res1, const float* __restrict__ res2,
    const float* __restrict__ gamma, int Ni, int Ki)
{
  __shared__ float As[16][64];
  __shared__ float Bs[16][64];
  const int tid = threadIdx.x;
  const int tx = tid & 15, ty = tid >> 4;
  const int m0 = blockIdx.x * 64, n0 = blockIdx.y * 64;
  float acc[4][4] = {};
  const int ar = tid >> 2, ac = (tid & 3) << 2;
  const int br = tid >> 4, bc = (tid & 15) << 2;
  for (int k0 = 0; k0 < Ki; k0 += 16){
    float4 av = *(const float4*)(A + (size_t)(m0 + ar) * Ki + k0 + ac);
    As[ac+0][ar]=av.x; As[ac+1][ar]=av.y; As[ac+2][ar]=av.z; As[ac+3][ar]=av.w;
    float4 bv = make_float4(0.f,0.f,0.f,0.f);
    if (n0 + bc < Ni) bv = *(const float4*)(Bw + (size_t)(k0 + br) * Ni + n0 + bc);
    *(float4*)&Bs[br][bc] = bv;
    __syncthreads();
    #pragma unroll
    for (int k = 0; k < 16; ++k){
      float4 aq = *(const float4*)&As[k][ty<<2];
      float4 bq = *(const float4*)&Bs[k][tx<<2];
      float a4[4] = {aq.x,aq.y,aq.z,aq.w};
      float b4[4] = {bq.x,bq.y,bq.z,bq.w};
      #pragma unroll
      for (int i=0;i<4;i++)
        #pragma unroll
        for (int j=0;j<4;j++)
          acc[i][j] += a4[i]*b4[j];
    }
    __syncthreads();
  }
  #pragma unroll
  for (int i=0;i<4;i++){
    int m = m0 + (ty<<2) + i;
    #pragma unroll
    for (int j=0;j<4;j++){
      int n = n0 + (tx<<2) + j;
      if (n < Ni){
        size_t o = (size_t)m * Ni + n;
        float v = acc[i][j] + bias[n];
        if constexpr (EP == 1) v = gelu_f(v);
        if constexpr (EP == 2) v = res1[o] + v;
        if constexpr (EP == 3) v = res1[o] + res2[o] + gamma[n] * v;
        Out[o] = v;
      }
    }
  }
}

// mask softmax over K=9, one thread per (pixel, g)
__global__ __launch_bounds__(256) void k_softmax9(float* __restrict__ msk){
  int t = blockIdx.x*256 + threadIdx.x;
  if (t >= M_*G_) return;
  float* p = msk + (size_t)t*9;
  float mx = p[0];
  for (int k=1;k<9;k++) mx = fmaxf(mx, p[k]);
  float s = 0.f;
  float e[9];
  for (int k=0;k<9;k++){ e[k] = expf(p[k]-mx); s += e[k]; }
  float r = 1.f/s;
  for (int k=0;k<9;k++) p[k] = e[k]*r;
}

// DCNv3 bilinear sampling + mask-weighted sum over K.
// block = pixel (256 threads: g = tid>>4, cg = tid&15)
__global__ __launch_bounds__(256) void k_dcn(const float* __restrict__ xp, const float* __restrict__ off,
    const float* __restrict__ msk, float* __restrict__ S){
  int pix = blockIdx.x;
  int g = threadIdx.x >> 4, cg = threadIdx.x & 15;
  int b = pix >> 12, hw = pix & 4095, h = hw >> 6, ww = hw & 63;
  const float* offp = off + (size_t)pix*OFFN_ + g*18;
  const float* mp   = msk + (size_t)pix*MSKN_ + g*9;
  const float* xpb  = xp + ((size_t)b*HW_)*C_ + g*16 + cg;
  float acc = 0.f;
  #pragma unroll
  for (int k=0;k<9;k++){
    float ox = offp[k*2+0], oy = offp[k*2+1];
    float m  = mp[k];
    float px = (float)(ww + (k%3)) + ox;   // padded-frame x minus 0.5 shift folded in
    float py = (float)(h  + (k/3)) + oy;
    int x0 = (int)floorf(px), y0 = (int)floorf(py);
    float fx = px - (float)x0, fy = py - (float)y0;
    #define FETCH(yy,xx) (((yy)>=1 && (yy)<=H_ && (xx)>=1 && (xx)<=W_) ? xpb[((size_t)((yy)-1)*W_ + ((xx)-1))*C_] : 0.f)
    float v00 = FETCH(y0,   x0  );
    float v01 = FETCH(y0,   x0+1);
    float v10 = FETCH(y0+1, x0  );
    float v11 = FETCH(y0+1, x0+1);
    #undef FETCH
    float top = v00*(1.f-fx) + v01*fx;
    float bot = v10*(1.f-fx) + v11*fx;
    acc += m * (top*(1.f-fy) + bot*fy);
  }
  S[(size_t)pix*C_ + g*16 + cg] = acc;
}

// bilinear 2x upsample (align_corners=False, edge clamp)
__global__ __launch_bounds__(256) void k_upsample(const float* __restrict__ T, float* __restrict__ U){
  int idx = blockIdx.x*256 + threadIdx.x;   // < 2*128*128*256 = 2^23
  int c  = idx & 255;
  int ox = (idx >> 8)  & 127;
  int oy = (idx >> 15) & 127;
  int b  = idx >> 22;
  float sy = oy*0.5f - 0.25f, sx = ox*0.5f - 0.25f;
  int y0 = (int)floorf(sy), x0 = (int)floorf(sx);
  float fy = sy - (float)y0, fx = sx - (float)x0;
  int y0c = min(max(y0,0),H_-1), y1c = min(max(y0+1,0),H_-1);
  int x0c = min(max(x0,0),W_-1), x1c = min(max(x0+1,0),W_-1);
  const float* tb = T + ((size_t)b*HW_)*C_ + c;
  float v00 = tb[((size_t)y0c*W_+x0c)*C_], v01 = tb[((size_t)y0c*W_+x1c)*C_];
  float v10 = tb[((size_t)y1c*W_+x0c)*C_], v11 = tb[((size_t)y1c*W_+x1c)*C_];
  U[idx] = (1.f-fy)*((1.f-fx)*v00 + fx*v01) + fy*((1.f-fx)*v10 + fx*v11);
}

// implicit-GEMM 3x3 conv, C=256 -> 128, SAME zero pad, on 128x128 grid
__global__ __launch_bounds__(256) void k_upconv(
    const float* __restrict__ U, const float* __restrict__ Bw,
    float* __restrict__ Out, const float* __restrict__ bias)
{
  __shared__ float As[16][64];
  __shared__ float Bs[16][64];
  const int tid = threadIdx.x;
  const int tx = tid & 15, ty = tid >> 4;
  const int m0 = blockIdx.x * 64, n0 = blockIdx.y * 64;
  float acc[4][4] = {};
  const int ar = tid >> 2, ac = (tid & 3) << 2;
  const int br = tid >> 4, bc = (tid & 15) << 2;
  const int m = m0 + ar;
  const int b = m >> 14, oy = (m >> 7) & 127, ox = m & 127;
  for (int k0 = 0; k0 < KUP_; k0 += 16){
    int k = k0 + ac;
    int tap = k >> 8, cc = k & 255;
    int dy = tap/3 - 1, dx = tap%3 - 1;
    int iy = oy + dy, ix = ox + dx;
    float4 av = make_float4(0.f,0.f,0.f,0.f);
    if (iy >= 0 && iy < UH_ && ix >= 0 && ix < UW_)
      av = *(const float4*)(U + (((size_t)b*UH_ + iy)*UW_ + ix)*C_ + cc);
    As[ac+0][ar]=av.x; As[ac+1][ar]=av.y; As[ac+2][ar]=av.z; As[ac+3][ar]=av.w;
    float4 bv = *(const float4*)(Bw + (size_t)(k0 + br)*NOUT_ + n0 + bc);
    *(float4*)&Bs[br][bc] = bv;
    __syncthreads();
    #pragma unroll
    for (int kk = 0; kk < 16; ++kk){
      float4 aq = *(const float4*)&As[kk][ty<<2];
      float4 bq = *(const float4*)&Bs[kk][tx<<2];
      float a4[4] = {aq.x,aq.y,aq.z,aq.w};
      float b4[4] = {bq.x,bq.y,bq.z,bq.w};
      #pragma unroll
      for (int i=0;i<4;i++)
        #pragma unroll
        for (int j=0;j<4;j++)
          acc[i][j] += a4[i]*b4[j];
    }
    __syncthreads();
  }
  #pragma unroll
  for (int i=0;i<4;i++){
    int mm = m0 + (ty<<2) + i;
    #pragma unroll
    for (int j=0;j<4;j++){
      int n = n0 + (tx<<2) + j;
      Out[(size_t)mm*NOUT_ + n] = acc[i][j] + bias[n];
    }
  }
}

// final LN over 128 channels + GELU -> d_out
__global__ __launch_bounds__(128) void k_out_ln_gelu(const float* __restrict__ In, float* __restrict__ Out,
    const float* __restrict__ g, const float* __restrict__ b){
  __shared__ float sm[12];
  int pix = blockIdx.x, c = threadIdx.x;
  float v = In[(size_t)pix*NOUT_ + c];
  float s = v, ss = v*v;
  block_sum2(s, ss, sm);
  float mean = s * (1.f/NOUT_), var = ss*(1.f/NOUT_) - mean*mean;
  float r = rsqrtf(var + 1e-6f);
  Out[(size_t)pix*NOUT_ + c] = gelu_f((v-mean)*r*g[c] + b[c]);
}

extern "C" void kernel_launch(void* const* d_in, const int* in_sizes, int n_in,
                              void* d_out, int out_size, void* d_ws, size_t ws_size,
                              hipStream_t stream)
{
  (void)in_sizes; (void)n_in; (void)out_size; (void)ws_size;
  const float* x_in = (const float*)d_in[0];
  float* ws = (float*)d_ws;
  // workspace layout (float offsets)
  float* X    = ws;                 // 2,097,152
  float* T    = ws + 2097152;       // 2,097,152
  float* XP   = ws + 4194304;       // 2,097,152 (xp / dw7-ln out)
  float* F    = ws + 6291456;       // 2,097,152
  float* OFF  = ws + 8388608;       // 2,359,296
  float* MSK  = ws + 10747904;      // 1,179,648
  float* S    = ws + 11927552;      // 2,097,152
  float* MID  = ws + 14024704;      // 8,388,608 (ffn hidden / upsample buffer)
  float* C2   = ws;                 // 4,194,304 overlays X+T (both dead at final stage)
  float* psum = ws + 22413312;      // 8192
  float* pmax = psum + 8192;
  float* ca   = pmax + 8192;        // 512
  float* smean= ca + 512;           // 8192
  float* smax = smean + 8192;       // 8192
  float* sa   = smax + 8192;        // 8192

  // ---- CBAM ----
  k_chpool<<<dim3(16,2),256,0,stream>>>(x_in, psum, pmax);
  k_ca<<<1,512,0,stream>>>(psum, pmax, (const float*)d_in[26], (const float*)d_in[27], ca);
  k_apply_ca<<<M_,256,0,stream>>>(x_in, X, ca, smean, smax);
  k_sa<<<M_/256,256,0,stream>>>(smean, smax, (const float*)d_in[28], sa);
  k_mul_ln<<<M_,256,0,stream>>>(X, sa, (const float*)d_in[29], (const float*)d_in[30]);

  // ---- layers ----
  for (int i=0;i<2;i++){
    const float* ln1g = (const float*)d_in[1] + i*C_;
    const float* ln1b = (const float*)d_in[2] + i*C_;
    const float* dww  = (const float*)d_in[3] + i*9*C_;
    const float* dwb  = (const float*)d_in[4] + i*C_;
    const float* dwng = (const float*)d_in[5] + i*C_;
    const float* dwnb = (const float*)d_in[6] + i*C_;
    const float* offw = (const float*)d_in[7] + (size_t)i*C_*OFFN_;
    const float* offb = (const float*)d_in[8] + i*OFFN_;
    const float* mskw = (const float*)d_in[9] + (size_t)i*C_*MSKN_;
    const float* mskb = (const float*)d_in[10] + i*MSKN_;
    const float* inpw = (const float*)d_in[11] + (size_t)i*C_*C_;
    const float* inpb = (const float*)d_in[12] + i*C_;
    const float* outw = (const float*)d_in[13] + (size_t)i*C_*C_;
    const float* outb = (const float*)d_in[14] + i*C_;
    const float* ln2g = (const float*)d_in[15] + i*C_;
    const float* ln2b = (const float*)d_in[16] + i*C_;
    const float* dcw  = (const float*)d_in[17] + i*49*C_;
    const float* dcb  = (const float*)d_in[18] + i*C_;
    const float* fng  = (const float*)d_in[19] + i*C_;
    const float* fnb  = (const float*)d_in[20] + i*C_;
    const float* c1w  = (const float*)d_in[21] + (size_t)i*C_*C4_;
    const float* c1b  = (const float*)d_in[22] + i*C4_;
    const float* c2w  = (const float*)d_in[23] + (size_t)i*C4_*C_;
    const float* c2b  = (const float*)d_in[24] + i*C_;
    const float* gam  = (const float*)d_in[25] + i*C_;

    // DCNv3 branch
    k_ln<<<M_,256,0,stream>>>(X, T, ln1g, ln1b);
    k_gemm<0><<<dim3(M_/64,4),256,0,stream>>>(T, inpw, XP, inpb, nullptr,nullptr,nullptr, C_, C_);
    k_dw3<<<M_,256,0,stream>>>(T, F, dww, dwb, dwng, dwnb);
    k_gemm<0><<<dim3(M_/64,5),256,0,stream>>>(F, offw, OFF, offb, nullptr,nullptr,nullptr, OFFN_, C_);
    k_gemm<0><<<dim3(M_/64,3),256,0,stream>>>(F, mskw, MSK, mskb, nullptr,nullptr,nullptr, MSKN_, C_);
    k_softmax9<<<(M_*G_+255)/256,256,0,stream>>>(MSK);
    k_dcn<<<M_,256,0,stream>>>(XP, OFF, MSK, S);
    k_gemm<2><<<dim3(M_/64,4),256,0,stream>>>(S, outw, X, outb, X, nullptr, nullptr, C_, C_);

    // LEFFN branch
    k_ln<<<M_,256,0,stream>>>(X, T, ln2g, ln2b);
    k_dw7<<<M_,256,0,stream>>>(T, XP, dcw, dcb, fng, fnb);
    k_gemm<1><<<dim3(M_/64,16),256,0,stream>>>(XP, c1w, MID, c1b, nullptr,nullptr,nullptr, C4_, C_);
    k_gemm<3><<<dim3(M_/64,4),256,0,stream>>>(MID, c2w, X, c2b, X, T, gam, C_, C4_);
  }

  // ---- final LN + upsample + conv + LN+GELU ----
  k_ln<<<M_,256,0,stream>>>(X, T, (const float*)d_in[31], (const float*)d_in[32]);
  k_upsample<<<(B_*UH_*UW_*C_)/256,256,0,stream>>>(T, MID);
  k_upconv<<<dim3(MUP_/64,2),256,0,stream>>>(MID, (const float*)d_in[33], C2, (const float*)d_in[34]);
  k_out_ln_gelu<<<MUP_,128,0,stream>>>(C2, (float*)d_out, (const float*)d_in[35], (const float*)d_in[36]);
}

// Round 2
// 724.885 us; speedup vs baseline: 1.7116x; 1.7116x over previous
//
#include <hip/hip_runtime.h>
#include <math.h>

#define B_ 2
#define H_ 64
#define W_ 64
#define C_ 256
#define G_ 16
#define HW_ (H_*W_)          // 4096
#define M_ (B_*HW_)          // 8192
#define C4_ (4*C_)           // 1024
#define OFFN_ 288
#define MSKN_ 144
#define UH_ 128
#define UW_ 128
#define MUP_ (B_*UH_*UW_)    // 32768
#define KUP_ (9*C_)          // 2304
#define NOUT_ 128

typedef short short8 __attribute__((ext_vector_type(8)));
typedef float f32x4 __attribute__((ext_vector_type(4)));
typedef unsigned short us4 __attribute__((ext_vector_type(4)));

__device__ __forceinline__ float gelu_f(float x){
  return 0.5f * x * (1.f + erff(x * 0.70710678118654752440f));
}
__device__ __forceinline__ float sigmoid_f(float x){ return 1.f/(1.f+expf(-x)); }
__device__ __forceinline__ unsigned short f2bf(float x){
  unsigned int u = __float_as_uint(x);
  unsigned int r = (u + 0x7fffu + ((u>>16)&1u)) >> 16;
  return (unsigned short)r;
}

__device__ __forceinline__ void block_sum2(float& s, float& ss, float* sm){
  #pragma unroll
  for (int off=32; off>0; off>>=1){ s += __shfl_down(s, off); ss += __shfl_down(ss, off); }
  int lane = threadIdx.x & 63, wid = threadIdx.x >> 6;
  if (lane == 0){ sm[wid] = s; sm[4+wid] = ss; }
  __syncthreads();
  float a = 0.f, b = 0.f;
  int nw = blockDim.x >> 6;
  for (int i=0;i<nw;i++){ a += sm[i]; b += sm[4+i]; }
  s = a; ss = b;
}

__device__ __forceinline__ void block_summax(float& s, float& m, float* sm){
  #pragma unroll
  for (int off=32; off>0; off>>=1){ s += __shfl_down(s, off); m = fmaxf(m, __shfl_down(m, off)); }
  int lane = threadIdx.x & 63, wid = threadIdx.x >> 6;
  if (lane == 0){ sm[wid] = s; sm[4+wid] = m; }
  __syncthreads();
  float a = 0.f, b = -3.4e38f;
  int nw = blockDim.x >> 6;
  for (int i=0;i<nw;i++){ a += sm[i]; b = fmaxf(b, sm[4+i]); }
  s = a; m = b;
}

// ---------------- weight prep: W[K][N] fp32 -> Wt[N][K] bf16 ----------------
__global__ __launch_bounds__(256) void k_wt(const float* __restrict__ W, unsigned short* __restrict__ Wt,
    int Kd, int Nd){
  __shared__ float tile[32][33];
  int k0 = blockIdx.x*32, n0 = blockIdx.y*32;
  int t = threadIdx.x;
  int r = t>>3, c4 = (t&7)*4;
  float4 v = make_float4(0.f,0.f,0.f,0.f);
  if (n0 + c4 < Nd) v = *(const float4*)(W + (size_t)(k0+r)*Nd + n0 + c4);
  tile[c4+0][r]=v.x; tile[c4+1][r]=v.y; tile[c4+2][r]=v.z; tile[c4+3][r]=v.w;
  __syncthreads();
  if (n0 + r < Nd){
    us4 o;
    o.x = f2bf(tile[r][c4+0]); o.y = f2bf(tile[r][c4+1]);
    o.z = f2bf(tile[r][c4+2]); o.w = f2bf(tile[r][c4+3]);
    *(us4*)(Wt + (size_t)(n0+r)*Kd + k0 + c4) = o;
  }
}

// ---------------- CBAM ----------------
__global__ __launch_bounds__(256) void k_chpool(const float* __restrict__ Xin,
      float* __restrict__ psum, float* __restrict__ pmax){
  int chunk = blockIdx.x, b = blockIdx.y; int c = threadIdx.x;
  const float* p = Xin + (((size_t)b*HW_) + chunk*256)*C_ + c;
  float s = 0.f, m = -3.4e38f;
  for (int i=0;i<256;i++){ float v = p[(size_t)i*C_]; s += v; m = fmaxf(m, v); }
  psum[(b*16+chunk)*C_+c] = s; pmax[(b*16+chunk)*C_+c] = m;
}

__global__ __launch_bounds__(512) void k_ca(const float* __restrict__ psum, const float* __restrict__ pmax,
    const float* __restrict__ w1, const float* __restrict__ w2, float* __restrict__ ca){
  __shared__ float pm[2][256], px[2][256], hh[2][2][16];
  int t = threadIdx.x;
  {
    int b = t >> 8, c = t & 255;
    float s = 0.f, m = -3.4e38f;
    for (int ch=0; ch<16; ch++){ s += psum[(b*16+ch)*256+c]; m = fmaxf(m, pmax[(b*16+ch)*256+c]); }
    pm[b][c] = s * (1.f/4096.f); px[b][c] = m;
  }
  __syncthreads();
  if (t < 64){
    int b = t >> 5, typ = (t >> 4) & 1, j = t & 15;
    const float* src = typ ? px[b] : pm[b];
    float a = 0.f;
    for (int c2=0;c2<256;c2++) a += src[c2]*w1[c2*16+j];
    hh[b][typ][j] = fmaxf(a, 0.f);
  }
  __syncthreads();
  {
    int b = t >> 8, c = t & 255;
    float a = 0.f;
    for (int j=0;j<16;j++) a += (hh[b][0][j]+hh[b][1][j]) * w2[j*256+c];
    ca[b*256+c] = sigmoid_f(a);
  }
}

__global__ __launch_bounds__(256) void k_apply_ca(const float* __restrict__ Xin, float* __restrict__ X,
    const float* __restrict__ ca, float* __restrict__ smean, float* __restrict__ smax){
  __shared__ float sm[12];
  int pix = blockIdx.x, c = threadIdx.x;
  int b = pix >> 12;
  float v = Xin[(size_t)pix*C_+c] * ca[b*C_+c];
  X[(size_t)pix*C_+c] = v;
  float s = v, m = v;
  block_summax(s, m, sm);
  if (c == 0){ smean[pix] = s * (1.f/C_); smax[pix] = m; }
}

__global__ __launch_bounds__(256) void k_sa(const float* __restrict__ smean, const float* __restrict__ smax,
    const float* __restrict__ w, float* __restrict__ sa){
  int pix = blockIdx.x*256 + threadIdx.x;
  if (pix >= M_) return;
  int b = pix >> 12, hw = pix & 4095, h = hw >> 6, ww = hw & 63;
  float s = 0.f;
  for (int ky=0;ky<7;ky++){
    int hh = h + ky - 3; if (hh < 0 || hh >= H_) continue;
    for (int kx=0;kx<7;kx++){
      int xx = ww + kx - 3; if (xx < 0 || xx >= W_) continue;
      int q = (b<<12) + (hh<<6) + xx;
      s += smean[q]*w[(ky*7+kx)*2+0] + smax[q]*w[(ky*7+kx)*2+1];
    }
  }
  sa[pix] = sigmoid_f(s);
}

__global__ __launch_bounds__(256) void k_mul_ln(float* __restrict__ X, const float* __restrict__ sa,
    const float* __restrict__ g, const float* __restrict__ b){
  __shared__ float sm[12];
  int pix = blockIdx.x, c = threadIdx.x;
  float v = X[(size_t)pix*C_+c] * sa[pix];
  float s = v, ss = v*v;
  block_sum2(s, ss, sm);
  float mean = s * (1.f/C_), var = ss*(1.f/C_) - mean*mean;
  float r = rsqrtf(var + 1e-6f);
  X[(size_t)pix*C_+c] = (v-mean)*r*g[c] + b[c];
}

// LN; optional bf16 secondary output
__global__ __launch_bounds__(256) void k_ln(const float* __restrict__ In, float* __restrict__ Out,
    unsigned short* __restrict__ Outb, const float* __restrict__ g, const float* __restrict__ b){
  __shared__ float sm[12];
  int pix = blockIdx.x, c = threadIdx.x;
  float v = In[(size_t)pix*C_+c];
  float s = v, ss = v*v;
  block_sum2(s, ss, sm);
  float mean = s * (1.f/C_), var = ss*(1.f/C_) - mean*mean;
  float r = rsqrtf(var + 1e-6f);
  float o = (v-mean)*r*g[c] + b[c];
  Out[(size_t)pix*C_+c] = o;
  if (Outb) Outb[(size_t)pix*C_+c] = f2bf(o);
}

// depthwise 3x3 + bias + LN + GELU -> bf16
__global__ __launch_bounds__(256) void k_dw3(const float* __restrict__ T, unsigned short* __restrict__ F,
    const float* __restrict__ w, const float* __restrict__ bias,
    const float* __restrict__ g, const float* __restrict__ bb){
  __shared__ float sm[12];
  int pix = blockIdx.x, c = threadIdx.x;
  int b = pix >> 12, hw = pix & 4095, h = hw >> 6, ww = hw & 63;
  float acc = bias[c];
  for (int ky=0;ky<3;ky++){
    int hh = h + ky - 1; if (hh < 0 || hh >= H_) continue;
    for (int kx=0;kx<3;kx++){
      int xx = ww + kx - 1; if (xx < 0 || xx >= W_) continue;
      acc += T[(((size_t)b*H_+hh)*W_+xx)*C_ + c] * w[(ky*3+kx)*C_ + c];
    }
  }
  float s = acc, ss = acc*acc;
  block_sum2(s, ss, sm);
  float mean = s * (1.f/C_), var = ss*(1.f/C_) - mean*mean;
  float r = rsqrtf(var + 1e-6f);
  F[(size_t)pix*C_ + c] = f2bf(gelu_f((acc-mean)*r*g[c] + bb[c]));
}

// depthwise 7x7 + bias + LN -> bf16
__global__ __launch_bounds__(256) void k_dw7(const float* __restrict__ T, unsigned short* __restrict__ Out,
    const float* __restrict__ w, const float* __restrict__ bias,
    const float* __restrict__ g, const float* __restrict__ bb){
  __shared__ float sm[12];
  int pix = blockIdx.x, c = threadIdx.x;
  int b = pix >> 12, hw = pix & 4095, h = hw >> 6, ww = hw & 63;
  float acc = bias[c];
  for (int ky=0;ky<7;ky++){
    int hh = h + ky - 3; if (hh < 0 || hh >= H_) continue;
    for (int kx=0;kx<7;kx++){
      int xx = ww + kx - 3; if (xx < 0 || xx >= W_) continue;
      acc += T[(((size_t)b*H_+hh)*W_+xx)*C_ + c] * w[(ky*7+kx)*C_ + c];
    }
  }
  float s = acc, ss = acc*acc;
  block_sum2(s, ss, sm);
  float mean = s * (1.f/C_), var = ss*(1.f/C_) - mean*mean;
  float r = rsqrtf(var + 1e-6f);
  Out[(size_t)pix*C_ + c] = f2bf((acc-mean)*r*g[c] + bb[c]);
}

// ---------------- bf16 MFMA GEMM ----------------
// Out[M,N] = A[M,K](bf16) @ Bt[N,K](bf16)^T, epilogues like before.
// TM in {64,128}, TN=128. block=256 (4 waves, 2x2), wave tile (TM/2)x64.
template<int TM, int EP, int OUTBF>
__global__ __launch_bounds__(256) void k_gemm_mfma(
    const unsigned short* __restrict__ A, const unsigned short* __restrict__ Bt,
    void* __restrict__ OutV, const float* __restrict__ bias,
    const float* __restrict__ res1, const float* __restrict__ res2,
    const float* __restrict__ gamma, int Ni, int Ki)
{
  constexpr int LD = 40;
  __shared__ unsigned short As[TM*LD];
  __shared__ unsigned short Bs[128*LD];
  const int tid = threadIdx.x;
  const int wave = tid >> 6, lane = tid & 63;
  const int m0 = blockIdx.x * TM, n0 = blockIdx.y * 128;
  const int wm0 = (wave >> 1) * (TM/2);
  const int wn0 = (wave & 1) * 64;
  constexpr int MI = TM/32;
  f32x4 acc[MI][4] = {};
  const int lm = lane & 15, kq = lane >> 4;
  constexpr int ACH = TM*4/256;   // A 16B-chunks per thread

  for (int k0 = 0; k0 < Ki; k0 += 32){
    #pragma unroll
    for (int i=0;i<ACH;i++){
      int ch = tid*ACH + i;
      int r = ch >> 2, cc = (ch & 3) * 8;
      short8 v = *(const short8*)(A + (size_t)(m0 + r)*Ki + k0 + cc);
      *(short8*)(As + r*LD + cc) = v;
    }
    #pragma unroll
    for (int i=0;i<2;i++){
      int ch = tid*2 + i;
      int r = ch >> 2, cc = (ch & 3) * 8;
      short8 v = {};
      if (n0 + r < Ni) v = *(const short8*)(Bt + (size_t)(n0 + r)*Ki + k0 + cc);
      *(short8*)(Bs + r*LD + cc) = v;
    }
    __syncthreads();
    short8 af[MI], bf[4];
    #pragma unroll
    for (int mi=0;mi<MI;mi++) af[mi] = *(const short8*)(As + (wm0 + mi*16 + lm)*LD + kq*8);
    #pragma unroll
    for (int ni=0;ni<4;ni++)  bf[ni] = *(const short8*)(Bs + (wn0 + ni*16 + lm)*LD + kq*8);
    #pragma unroll
    for (int mi=0;mi<MI;mi++)
      #pragma unroll
      for (int ni=0;ni<4;ni++)
        acc[mi][ni] = __builtin_amdgcn_mfma_f32_16x16x32_bf16(af[mi], bf[ni], acc[mi][ni], 0,0,0);
    __syncthreads();
  }
  #pragma unroll
  for (int mi=0;mi<MI;mi++){
    #pragma unroll
    for (int ni=0;ni<4;ni++){
      int n = n0 + wn0 + ni*16 + lm;
      if (n < Ni){
        float bv = bias[n];
        #pragma unroll
        for (int r=0;r<4;r++){
          int m = m0 + wm0 + mi*16 + kq*4 + r;
          size_t o = (size_t)m*Ni + n;
          float v = acc[mi][ni][r] + bv;
          if constexpr (EP==1) v = gelu_f(v);
          if constexpr (EP==2) v = res1[o] + v;
          if constexpr (EP==3) v = res1[o] + res2[o] + gamma[n]*v;
          if constexpr (OUTBF) ((unsigned short*)OutV)[o] = f2bf(v);
          else                 ((float*)OutV)[o] = v;
        }
      }
    }
  }
}

// mask softmax over K=9
__global__ __launch_bounds__(256) void k_softmax9(float* __restrict__ msk){
  int t = blockIdx.x*256 + threadIdx.x;
  if (t >= M_*G_) return;
  float* p = msk + (size_t)t*9;
  float mx = p[0];
  for (int k=1;k<9;k++) mx = fmaxf(mx, p[k]);
  float s = 0.f;
  float e[9];
  for (int k=0;k<9;k++){ e[k] = expf(p[k]-mx); s += e[k]; }
  float r = 1.f/s;
  for (int k=0;k<9;k++) p[k] = e[k]*r;
}

// DCNv3 sampling -> bf16
__global__ __launch_bounds__(256) void k_dcn(const float* __restrict__ xp, const float* __restrict__ off,
    const float* __restrict__ msk, unsigned short* __restrict__ S){
  int pix = blockIdx.x;
  int g = threadIdx.x >> 4, cg = threadIdx.x & 15;
  int b = pix >> 12, hw = pix & 4095, h = hw >> 6, ww = hw & 63;
  const float* offp = off + (size_t)pix*OFFN_ + g*18;
  const float* mp   = msk + (size_t)pix*MSKN_ + g*9;
  const float* xpb  = xp + ((size_t)b*HW_)*C_ + g*16 + cg;
  float acc = 0.f;
  #pragma unroll
  for (int k=0;k<9;k++){
    float ox = offp[k*2+0], oy = offp[k*2+1];
    float m  = mp[k];
    float px = (float)(ww + (k%3)) + ox;
    float py = (float)(h  + (k/3)) + oy;
    int x0 = (int)floorf(px), y0 = (int)floorf(py);
    float fx = px - (float)x0, fy = py - (float)y0;
    #define FETCH(yy,xx) (((yy)>=1 && (yy)<=H_ && (xx)>=1 && (xx)<=W_) ? xpb[((size_t)((yy)-1)*W_ + ((xx)-1))*C_] : 0.f)
    float v00 = FETCH(y0,   x0  );
    float v01 = FETCH(y0,   x0+1);
    float v10 = FETCH(y0+1, x0  );
    float v11 = FETCH(y0+1, x0+1);
    #undef FETCH
    float top = v00*(1.f-fx) + v01*fx;
    float bot = v10*(1.f-fx) + v11*fx;
    acc += m * (top*(1.f-fy) + bot*fy);
  }
  S[(size_t)pix*C_ + g*16 + cg] = f2bf(acc);
}

// bilinear 2x upsample -> bf16
__global__ __launch_bounds__(256) void k_upsample(const float* __restrict__ T, unsigned short* __restrict__ U){
  int idx = blockIdx.x*256 + threadIdx.x;
  int c  = idx & 255;
  int ox = (idx >> 8)  & 127;
  int oy = (idx >> 15) & 127;
  int b  = idx >> 22;
  float sy = oy*0.5f - 0.25f, sx = ox*0.5f - 0.25f;
  int y0 = (int)floorf(sy), x0 = (int)floorf(sx);
  float fy = sy - (float)y0, fx = sx - (float)x0;
  int y0c = min(max(y0,0),H_-1), y1c = min(max(y0+1,0),H_-1);
  int x0c = min(max(x0,0),W_-1), x1c = min(max(x0+1,0),W_-1);
  const float* tb = T + ((size_t)b*HW_)*C_ + c;
  float v00 = tb[((size_t)y0c*W_+x0c)*C_], v01 = tb[((size_t)y0c*W_+x1c)*C_];
  float v10 = tb[((size_t)y1c*W_+x0c)*C_], v11 = tb[((size_t)y1c*W_+x1c)*C_];
  U[idx] = f2bf((1.f-fy)*((1.f-fx)*v00 + fx*v01) + fy*((1.f-fx)*v10 + fx*v11));
}

// implicit-GEMM 3x3 conv via MFMA: U bf16 [MUP,256] -> Out fp32 [MUP,128]
__global__ __launch_bounds__(256) void k_upconv_mfma(
    const unsigned short* __restrict__ U, const unsigned short* __restrict__ Wt,  // Wt[128][2304]
    float* __restrict__ Out, const float* __restrict__ bias)
{
  constexpr int LD = 40;
  __shared__ unsigned short As[128*LD];
  __shared__ unsigned short Bs[128*LD];
  const int tid = threadIdx.x;
  const int wave = tid >> 6, lane = tid & 63;
  const int m0 = blockIdx.x * 128;
  const int wm0 = (wave >> 1) * 64;
  const int wn0 = (wave & 1) * 64;
  f32x4 acc[4][4] = {};
  const int lm = lane & 15, kq = lane >> 4;

  for (int k0 = 0; k0 < KUP_; k0 += 32){
    int tap = k0 >> 8, cc0 = k0 & 255;
    int dy = tap/3 - 1, dx = tap%3 - 1;
    #pragma unroll
    for (int i=0;i<2;i++){
      int ch = tid*2 + i;
      int r = ch >> 2, cc = (ch & 3) * 8;
      int m = m0 + r;
      int b = m >> 14, oy = (m >> 7) & 127, ox = m & 127;
      int iy = oy + dy, ix = ox + dx;
      short8 v = {};
      if (iy >= 0 && iy < UH_ && ix >= 0 && ix < UW_)
        v = *(const short8*)(U + (((size_t)b*UH_ + iy)*UW_ + ix)*C_ + cc0 + cc);
      *(short8*)(As + r*LD + cc) = v;
    }
    #pragma unroll
    for (int i=0;i<2;i++){
      int ch = tid*2 + i;
      int r = ch >> 2, cc = (ch & 3) * 8;
      short8 v = *(const short8*)(Wt + (size_t)r*KUP_ + k0 + cc);
      *(short8*)(Bs + r*LD + cc) = v;
    }
    __syncthreads();
    short8 af[4], bf[4];
    #pragma unroll
    for (int mi=0;mi<4;mi++) af[mi] = *(const short8*)(As + (wm0 + mi*16 + lm)*LD + kq*8);
    #pragma unroll
    for (int ni=0;ni<4;ni++) bf[ni] = *(const short8*)(Bs + (wn0 + ni*16 + lm)*LD + kq*8);
    #pragma unroll
    for (int mi=0;mi<4;mi++)
      #pragma unroll
      for (int ni=0;ni<4;ni++)
        acc[mi][ni] = __builtin_amdgcn_mfma_f32_16x16x32_bf16(af[mi], bf[ni], acc[mi][ni], 0,0,0);
    __syncthreads();
  }
  #pragma unroll
  for (int mi=0;mi<4;mi++){
    #pragma unroll
    for (int ni=0;ni<4;ni++){
      int n = wn0 + ni*16 + lm;
      float bv = bias[n];
      #pragma unroll
      for (int r=0;r<4;r++){
        int m = m0 + wm0 + mi*16 + kq*4 + r;
        Out[(size_t)m*NOUT_ + n] = acc[mi][ni][r] + bv;
      }
    }
  }
}

// final LN over 128 channels + GELU -> d_out
__global__ __launch_bounds__(128) void k_out_ln_gelu(const float* __restrict__ In, float* __restrict__ Out,
    const float* __restrict__ g, const float* __restrict__ b){
  __shared__ float sm[12];
  int pix = blockIdx.x, c = threadIdx.x;
  float v = In[(size_t)pix*NOUT_ + c];
  float s = v, ss = v*v;
  block_sum2(s, ss, sm);
  float mean = s * (1.f/NOUT_), var = ss*(1.f/NOUT_) - mean*mean;
  float r = rsqrtf(var + 1e-6f);
  Out[(size_t)pix*NOUT_ + c] = gelu_f((v-mean)*r*g[c] + b[c]);
}

extern "C" void kernel_launch(void* const* d_in, const int* in_sizes, int n_in,
                              void* d_out, int out_size, void* d_ws, size_t ws_size,
                              hipStream_t stream)
{
  (void)in_sizes; (void)n_in; (void)out_size; (void)ws_size;
  const float* x_in = (const float*)d_in[0];
  char* w = (char*)d_ws;
  const size_t MB = 1u<<20;
  float* X    = (float*)(w + 0*MB);        // 8 MB
  float* T    = (float*)(w + 8*MB);        // 8 MB
  float* XP   = (float*)(w + 16*MB);       // 8 MB
  float* OFF  = (float*)(w + 24*MB);       // 9.4 MB
  float* MSK  = (float*)(w + 34*MB);       // 4.7 MB
  unsigned short* MIDb = (unsigned short*)(w + 39*MB);  // 16 MB (also U)
  unsigned short* Ub   = MIDb;
  unsigned short* Tb   = (unsigned short*)(w + 55*MB);  // 4 MB
  unsigned short* Fb   = (unsigned short*)(w + 59*MB);  // 4 MB
  unsigned short* XPb  = (unsigned short*)(w + 63*MB);  // 4 MB
  unsigned short* Sb   = (unsigned short*)(w + 67*MB);  // 4 MB
  unsigned short* WT   = (unsigned short*)(w + 71*MB);  // 3.7 MB
  float* C2   = (float*)(w + 0*MB);        // overlay X,T (dead at final stage)
  float* psum = (float*)(w + 75*MB);
  float* pmax = psum + 8192;
  float* ca   = pmax + 8192;
  float* smean= ca + 512;
  float* smax = smean + 8192;
  float* sa   = smax + 8192;

  // transposed bf16 weights
  unsigned short* WtInp[2], *WtOut[2], *WtOff[2], *WtMsk[2], *WtC1[2], *WtC2[2];
  {
    size_t o = 0;
    for (int i=0;i<2;i++){
      WtInp[i] = WT + o; o += 65536;
      WtOut[i] = WT + o; o += 65536;
      WtOff[i] = WT + o; o += 73728;
      WtMsk[i] = WT + o; o += 36864;
      WtC1[i]  = WT + o; o += 262144;
      WtC2[i]  = WT + o; o += 262144;
    }
  }
  unsigned short* WtUp = WT + 1531904;

  // ---- weight prep ----
  for (int i=0;i<2;i++){
    k_wt<<<dim3(8,8),256,0,stream>>>((const float*)d_in[11] + (size_t)i*C_*C_, WtInp[i], C_, C_);
    k_wt<<<dim3(8,8),256,0,stream>>>((const float*)d_in[13] + (size_t)i*C_*C_, WtOut[i], C_, C_);
    k_wt<<<dim3(8,9),256,0,stream>>>((const float*)d_in[7]  + (size_t)i*C_*OFFN_, WtOff[i], C_, OFFN_);
    k_wt<<<dim3(8,5),256,0,stream>>>((const float*)d_in[9]  + (size_t)i*C_*MSKN_, WtMsk[i], C_, MSKN_);
    k_wt<<<dim3(8,32),256,0,stream>>>((const float*)d_in[21] + (size_t)i*C_*C4_, WtC1[i], C_, C4_);
    k_wt<<<dim3(32,8),256,0,stream>>>((const float*)d_in[23] + (size_t)i*C4_*C_, WtC2[i], C4_, C_);
  }
  k_wt<<<dim3(72,4),256,0,stream>>>((const float*)d_in[33], WtUp, KUP_, NOUT_);

  // ---- CBAM ----
  k_chpool<<<dim3(16,2),256,0,stream>>>(x_in, psum, pmax);
  k_ca<<<1,512,0,stream>>>(psum, pmax, (const float*)d_in[26], (const float*)d_in[27], ca);
  k_apply_ca<<<M_,256,0,stream>>>(x_in, X, ca, smean, smax);
  k_sa<<<M_/256,256,0,stream>>>(smean, smax, (const float*)d_in[28], sa);
  k_mul_ln<<<M_,256,0,stream>>>(X, sa, (const float*)d_in[29], (const float*)d_in[30]);

  // ---- layers ----
  for (int i=0;i<2;i++){
    const float* ln1g = (const float*)d_in[1] + i*C_;
    const float* ln1b = (const float*)d_in[2] + i*C_;
    const float* dww  = (const float*)d_in[3] + i*9*C_;
    const float* dwb  = (const float*)d_in[4] + i*C_;
    const float* dwng = (const float*)d_in[5] + i*C_;
    const float* dwnb = (const float*)d_in[6] + i*C_;
    const float* offb = (const float*)d_in[8] + i*OFFN_;
    const float* mskb = (const float*)d_in[10] + i*MSKN_;
    const float* inpb = (const float*)d_in[12] + i*C_;
    const float* outb = (const float*)d_in[14] + i*C_;
    const float* ln2g = (const float*)d_in[15] + i*C_;
    const float* ln2b = (const float*)d_in[16] + i*C_;
    const float* dcw  = (const float*)d_in[17] + i*49*C_;
    const float* dcb  = (const float*)d_in[18] + i*C_;
    const float* fng  = (const float*)d_in[19] + i*C_;
    const float* fnb  = (const float*)d_in[20] + i*C_;
    const float* c1b  = (const float*)d_in[22] + i*C4_;
    const float* c2b  = (const float*)d_in[24] + i*C_;
    const float* gam  = (const float*)d_in[25] + i*C_;

    // DCNv3 branch
    k_ln<<<M_,256,0,stream>>>(X, T, Tb, ln1g, ln1b);
    k_gemm_mfma<64,0,0><<<dim3(M_/64,2),256,0,stream>>>(Tb, WtInp[i], XP, inpb, nullptr,nullptr,nullptr, C_, C_);
    k_dw3<<<M_,256,0,stream>>>(T, Fb, dww, dwb, dwng, dwnb);
    k_gemm_mfma<64,0,0><<<dim3(M_/64,3),256,0,stream>>>(Fb, WtOff[i], OFF, offb, nullptr,nullptr,nullptr, OFFN_, C_);
    k_gemm_mfma<64,0,0><<<dim3(M_/64,2),256,0,stream>>>(Fb, WtMsk[i], MSK, mskb, nullptr,nullptr,nullptr, MSKN_, C_);
    k_softmax9<<<(M_*G_+255)/256,256,0,stream>>>(MSK);
    k_dcn<<<M_,256,0,stream>>>(XP, OFF, MSK, Sb);
    k_gemm_mfma<64,2,0><<<dim3(M_/64,2),256,0,stream>>>(Sb, WtOut[i], X, outb, X, nullptr, nullptr, C_, C_);

    // LEFFN branch
    k_ln<<<M_,256,0,stream>>>(X, T, nullptr, ln2g, ln2b);
    k_dw7<<<M_,256,0,stream>>>(T, XPb, dcw, dcb, fng, fnb);
    k_gemm_mfma<128,1,1><<<dim3(M_/128,8),256,0,stream>>>(XPb, WtC1[i], MIDb, c1b, nullptr,nullptr,nullptr, C4_, C_);
    k_gemm_mfma<64,3,0><<<dim3(M_/64,2),256,0,stream>>>(MIDb, WtC2[i], X, c2b, X, T, gam, C_, C4_);
  }

  // ---- final LN + upsample + conv + LN+GELU ----
  k_ln<<<M_,256,0,stream>>>(X, T, nullptr, (const float*)d_in[31], (const float*)d_in[32]);
  k_upsample<<<(B_*UH_*UW_*C_)/256,256,0,stream>>>(T, Ub);
  k_upconv_mfma<<<MUP_/128,256,0,stream>>>(Ub, WtUp, C2, (const float*)d_in[34]);
  k_out_ln_gelu<<<MUP_,128,0,stream>>>(C2, (float*)d_out, (const float*)d_in[35], (const float*)d_in[36]);
}